// Round 1
// baseline (1999.648 us; speedup 1.0000x reference)
//
#include <hip/hip_runtime.h>
#include <hip/hip_bf16.h>

// Problem: CrossAttention  B=2, S=2048, D=1024, H=16, HD=64
// q = x@Wq+bq; k = y@Wk+bk; v = y@Wv+bv; causal softmax(q k^T/8) v; @Wo+bo
// Round 1: correct fp32 baseline. GEMMs = 64x64 tiles (BK=16), attention =
// flash-style per-64-row-Q-tile blocks with online softmax.

#define BDIM 2
#define SDIM 2048
#define DDIM 1024
#define HDIM 16
#define HD   64
#define MDIM (BDIM*SDIM)   // 4096
#define ATT_SCALE 0.125f   // 1/sqrt(64)

// ---------------- GEMM: C[M,N] = A[M,K] @ W[K,N] + bias[N] ----------------
// 64x64 tile, BK=16, 256 threads, 4x4 microtile per thread.
__global__ __launch_bounds__(256) void sgemm_bias_kernel(
    const float* __restrict__ A, const float* __restrict__ W,
    const float* __restrict__ bias, float* __restrict__ C,
    int Mdim, int Ndim, int Kdim)
{
    __shared__ float As[64][17];   // +1 pad: As[row][kk] column reads -> 2-way max
    __shared__ float Ws[16][64];
    const int t  = threadIdx.x;
    const int tx = t & 15, ty = t >> 4;
    const int bm = blockIdx.y * 64, bn = blockIdx.x * 64;
    const int lr = t >> 2, lc4 = t & 3;   // A-tile load: 64 rows x 4 float4
    const int wk = t >> 4, wn4 = t & 15;  // W-tile load: 16 rows x 16 float4

    float acc[4][4] = {};

    for (int kt = 0; kt < Kdim; kt += 16) {
        float4 a4 = *(const float4*)&A[(size_t)(bm + lr) * Kdim + kt + lc4 * 4];
        As[lr][lc4*4 + 0] = a4.x; As[lr][lc4*4 + 1] = a4.y;
        As[lr][lc4*4 + 2] = a4.z; As[lr][lc4*4 + 3] = a4.w;
        *(float4*)&Ws[wk][wn4*4] =
            *(const float4*)&W[(size_t)(kt + wk) * Ndim + bn + wn4 * 4];
        __syncthreads();
        #pragma unroll
        for (int kk = 0; kk < 16; ++kk) {
            float4 w4 = *(float4*)&Ws[kk][tx*4];
            float wv[4] = {w4.x, w4.y, w4.z, w4.w};
            #pragma unroll
            for (int i = 0; i < 4; ++i) {
                float a = As[ty*4 + i][kk];
                #pragma unroll
                for (int j = 0; j < 4; ++j) acc[i][j] += a * wv[j];
            }
        }
        __syncthreads();
    }

    float4 b4 = *(const float4*)&bias[bn + tx*4];
    #pragma unroll
    for (int i = 0; i < 4; ++i) {
        float4 o;
        o.x = acc[i][0] + b4.x; o.y = acc[i][1] + b4.y;
        o.z = acc[i][2] + b4.z; o.w = acc[i][3] + b4.w;
        *(float4*)&C[(size_t)(bm + ty*4 + i) * Ndim + bn + tx*4] = o;
    }
}

// ---------------- Flash-style causal attention ----------------
// One block = one (batch, head, 64-row Q tile). 256 threads:
// thread t -> row r = t>>2 (0..63), col-group cg = t&3 (16 cols / 16 dims).
// Q row held in registers; K/V/P 64x64 tiles in LDS (pad 68 for alignment).
__global__ __launch_bounds__(256) void flash_attn_kernel(
    const float* __restrict__ Q, const float* __restrict__ K,
    const float* __restrict__ V, float* __restrict__ O)
{
    __shared__ float Ks[64][68];
    __shared__ float Vs[64][68];
    __shared__ float Ps[64][68];

    const int qt = blockIdx.x;   // 0..31  q tile
    const int h  = blockIdx.y;   // 0..15
    const int b  = blockIdx.z;   // 0..1
    const int t  = threadIdx.x;
    const int r  = t >> 2, cg = t & 3;
    const int qi = qt * 64 + r;
    const size_t headoff = (size_t)h * HD;

    // Q row -> registers (64 floats)
    float q[64];
    {
        const float* Qrow = Q + ((size_t)(b * SDIM + qi) * DDIM + headoff);
        #pragma unroll
        for (int d4 = 0; d4 < 16; ++d4) {
            float4 v = *(const float4*)&Qrow[d4*4];
            q[d4*4+0] = v.x; q[d4*4+1] = v.y; q[d4*4+2] = v.z; q[d4*4+3] = v.w;
        }
    }

    float m = -1e30f, l = 0.0f;
    float o[16] = {};

    for (int kt = 0; kt <= qt; ++kt) {
        // stage K,V tiles: each thread loads 16 floats of its row slice
        {
            const size_t rowbase = (size_t)(b * SDIM + kt*64 + r) * DDIM + headoff + cg*16;
            const float* Kp = K + rowbase;
            const float* Vp = V + rowbase;
            #pragma unroll
            for (int j = 0; j < 4; ++j) {
                *(float4*)&Ks[r][cg*16 + j*4] = *(const float4*)&Kp[j*4];
                *(float4*)&Vs[r][cg*16 + j*4] = *(const float4*)&Vp[j*4];
            }
        }
        __syncthreads();

        // scores: 16 cols per thread, dot(q[64], K[col][64])
        float s[16];
        const bool diag = (kt == qt);
        #pragma unroll 4
        for (int c = 0; c < 16; ++c) {
            const int col = cg*16 + c;
            float acc = 0.0f;
            #pragma unroll
            for (int d4 = 0; d4 < 16; ++d4) {
                float4 k4 = *(float4*)&Ks[col][d4*4];
                acc += q[d4*4+0]*k4.x + q[d4*4+1]*k4.y
                     + q[d4*4+2]*k4.z + q[d4*4+3]*k4.w;
            }
            acc *= ATT_SCALE;
            if (diag && (kt*64 + col) > qi) acc = -1e30f;
            s[c] = acc;
        }

        // online softmax: reduce across the 4 lanes sharing a row
        float mx = s[0];
        #pragma unroll
        for (int c = 1; c < 16; ++c) mx = fmaxf(mx, s[c]);
        mx = fmaxf(mx, __shfl_xor(mx, 1));
        mx = fmaxf(mx, __shfl_xor(mx, 2));
        const float mnew  = fmaxf(m, mx);
        const float alpha = __expf(m - mnew);
        float rowsum = 0.0f;
        #pragma unroll
        for (int c = 0; c < 16; ++c) { s[c] = __expf(s[c] - mnew); rowsum += s[c]; }
        rowsum += __shfl_xor(rowsum, 1);
        rowsum += __shfl_xor(rowsum, 2);
        l = l * alpha + rowsum;
        m = mnew;
        #pragma unroll
        for (int d = 0; d < 16; ++d) o[d] *= alpha;

        #pragma unroll
        for (int c = 0; c < 16; ++c) Ps[r][cg*16 + c] = s[c];
        __syncthreads();

        // PV: o[cg*16 .. cg*16+15] += P[r][k] * V[k][dims]
        #pragma unroll 8
        for (int k = 0; k < 64; ++k) {
            const float p = Ps[r][k];
            #pragma unroll
            for (int j = 0; j < 4; ++j) {
                float4 v4 = *(float4*)&Vs[k][cg*16 + j*4];
                o[j*4+0] += p*v4.x; o[j*4+1] += p*v4.y;
                o[j*4+2] += p*v4.z; o[j*4+3] += p*v4.w;
            }
        }
        __syncthreads();
    }

    const float inv = 1.0f / l;
    float* Op = O + ((size_t)(b * SDIM + qi) * DDIM + headoff + cg*16);
    #pragma unroll
    for (int j = 0; j < 4; ++j) {
        float4 v;
        v.x = o[j*4+0]*inv; v.y = o[j*4+1]*inv;
        v.z = o[j*4+2]*inv; v.w = o[j*4+3]*inv;
        *(float4*)&Op[j*4] = v;
    }
}

extern "C" void kernel_launch(void* const* d_in, const int* in_sizes, int n_in,
                              void* d_out, int out_size, void* d_ws, size_t ws_size,
                              hipStream_t stream) {
    const float* x  = (const float*)d_in[0];
    const float* y  = (const float*)d_in[1];
    const float* Wq = (const float*)d_in[2];
    const float* bq = (const float*)d_in[3];
    const float* Wk = (const float*)d_in[4];
    const float* bk = (const float*)d_in[5];
    const float* Wv = (const float*)d_in[6];
    const float* bv = (const float*)d_in[7];
    const float* Wo = (const float*)d_in[8];
    const float* bo = (const float*)d_in[9];
    float* out = (float*)d_out;

    const size_t mat = (size_t)MDIM * DDIM;   // 4M floats = 16 MB
    float* wsQ = (float*)d_ws;
    float* wsK = wsQ + mat;
    float* wsV = wsK + mat;
    float* wsO = wsV + mat;

    dim3 gGemm(DDIM / 64, MDIM / 64);   // (16, 64)
    dim3 bGemm(256);
    hipLaunchKernelGGL(sgemm_bias_kernel, gGemm, bGemm, 0, stream,
                       x, Wq, bq, wsQ, MDIM, DDIM, DDIM);
    hipLaunchKernelGGL(sgemm_bias_kernel, gGemm, bGemm, 0, stream,
                       y, Wk, bk, wsK, MDIM, DDIM, DDIM);
    hipLaunchKernelGGL(sgemm_bias_kernel, gGemm, bGemm, 0, stream,
                       y, Wv, bv, wsV, MDIM, DDIM, DDIM);

    dim3 gAttn(SDIM / 64, HDIM, BDIM);  // (32, 16, 2)
    hipLaunchKernelGGL(flash_attn_kernel, gAttn, dim3(256), 0, stream,
                       wsQ, wsK, wsV, wsO);

    hipLaunchKernelGGL(sgemm_bias_kernel, gGemm, bGemm, 0, stream,
                       wsO, Wo, bo, out, MDIM, DDIM, DDIM);
}

// Round 2
// 798.598 us; speedup vs baseline: 2.5039x; 2.5039x over previous
//
#include <hip/hip_runtime.h>
#include <hip/hip_bf16.h>

// CrossAttention  B=2, S=2048, D=1024, H=16, HD=64
// R2: MFMA flash attention (bf16), fp32 GEMMs with bf16/transposed epilogues.

#define BDIM 2
#define SDIM 2048
#define DDIM 1024
#define HDIM 16
#define HD   64
#define MDIM (BDIM*SDIM)   // 4096
#define ATT_SCALE 0.125f   // 1/sqrt(64)

using short8  = __attribute__((ext_vector_type(8))) short;
using floatx4 = __attribute__((ext_vector_type(4))) float;

static __device__ __forceinline__ unsigned short f2bf(float x) {
    union { float f; unsigned int u; } c; c.f = x;
    unsigned int r = (c.u + 0x7fffu + ((c.u >> 16) & 1u)) >> 16;
    return (unsigned short)r;
}

// ---------------- GEMM: C[M,N] = A[M,K] @ W[K,N] + bias[N] ----------------
// MODE 0: fp32 row-major. MODE 1: bf16 row-major. MODE 2: bf16 per-head
// transposed: vT[(m>>11)*1024 + n][2048] <- value at column (m&2047).
template <int MODE>
__global__ __launch_bounds__(256) void sgemm_bias_kernel(
    const float* __restrict__ A, const float* __restrict__ W,
    const float* __restrict__ bias, void* __restrict__ Cout,
    int Mdim, int Ndim, int Kdim)
{
    __shared__ float As[64][17];
    __shared__ float Ws[16][64];
    const int t  = threadIdx.x;
    const int tx = t & 15, ty = t >> 4;
    const int bm = blockIdx.y * 64, bn = blockIdx.x * 64;
    const int lr = t >> 2, lc4 = t & 3;
    const int wk = t >> 4, wn4 = t & 15;

    float acc[4][4] = {};

    for (int kt = 0; kt < Kdim; kt += 16) {
        float4 a4 = *(const float4*)&A[(size_t)(bm + lr) * Kdim + kt + lc4 * 4];
        As[lr][lc4*4 + 0] = a4.x; As[lr][lc4*4 + 1] = a4.y;
        As[lr][lc4*4 + 2] = a4.z; As[lr][lc4*4 + 3] = a4.w;
        *(float4*)&Ws[wk][wn4*4] =
            *(const float4*)&W[(size_t)(kt + wk) * Ndim + bn + wn4 * 4];
        __syncthreads();
        #pragma unroll
        for (int kk = 0; kk < 16; ++kk) {
            float4 w4 = *(float4*)&Ws[kk][tx*4];
            float wv[4] = {w4.x, w4.y, w4.z, w4.w};
            #pragma unroll
            for (int i = 0; i < 4; ++i) {
                float a = As[ty*4 + i][kk];
                #pragma unroll
                for (int j = 0; j < 4; ++j) acc[i][j] += a * wv[j];
            }
        }
        __syncthreads();
    }

    float4 b4 = *(const float4*)&bias[bn + tx*4];
    float bv[4] = {b4.x, b4.y, b4.z, b4.w};

    #pragma unroll
    for (int i = 0; i < 4; ++i) {
        const int m = bm + ty*4 + i;
        if (MODE == 0) {
            float4 o;
            o.x = acc[i][0] + bv[0]; o.y = acc[i][1] + bv[1];
            o.z = acc[i][2] + bv[2]; o.w = acc[i][3] + bv[3];
            *(float4*)&((float*)Cout)[(size_t)m * Ndim + bn + tx*4] = o;
        } else if (MODE == 1) {
            ushort4 pk;
            pk.x = f2bf(acc[i][0] + bv[0]); pk.y = f2bf(acc[i][1] + bv[1]);
            pk.z = f2bf(acc[i][2] + bv[2]); pk.w = f2bf(acc[i][3] + bv[3]);
            *(ushort4*)&((unsigned short*)Cout)[(size_t)m * Ndim + bn + tx*4] = pk;
        } else {
            // vT[(b*1024 + n)][s], b = m>>11, s = m&2047
            #pragma unroll
            for (int j = 0; j < 4; ++j) {
                const int n = bn + tx*4 + j;
                ((unsigned short*)Cout)[((size_t)((m >> 11) * 1024 + n)) * SDIM + (m & 2047)]
                    = f2bf(acc[i][j] + bv[j]);
            }
        }
    }
}

// ---------------- MFMA flash attention ----------------
// Block: 256 thr = 4 waves; wave w owns 32 q rows (qb + w*32), iterates K in
// 32-key double-tiles. All fragments staged in LDS in frag-linear layout.
__global__ __launch_bounds__(256) void attn_mfma_kernel(
    const unsigned short* __restrict__ Qbf, const unsigned short* __restrict__ Kbf,
    const unsigned short* __restrict__ vT, float* __restrict__ O)
{
    __shared__ __align__(16) unsigned short KfL[4*64*8];   // (kt*2+kc, lane)
    __shared__ __align__(16) unsigned short VfL[4*64*8];   // (nch, lane)
    __shared__ __align__(16) unsigned short PfL[8*64*8];   // (wave*2+qsub, lane)

    const int t    = threadIdx.x;
    const int w    = t >> 6;
    const int l    = t & 63;
    const int quad = l >> 4, col = l & 15;
    const int qb   = blockIdx.x * 128;
    const int h    = blockIdx.y, b = blockIdx.z;
    const int qwb  = qb + w * 32;
    const size_t hoff = (size_t)h * HD;

    // Q fragments [qsub][kchunk] (A-layout: m=col, k=quad*8+j)
    short8 qf[2][2];
    #pragma unroll
    for (int qs = 0; qs < 2; ++qs)
        #pragma unroll
        for (int kc = 0; kc < 2; ++kc)
            qf[qs][kc] = *(const short8*)
                &Qbf[(size_t)(b*SDIM + qwb + qs*16 + col) * DDIM + hoff + kc*32 + quad*8];

    floatx4 o_[2][4] = {};
    float m_[2][4], L_[2][4];
    #pragma unroll
    for (int qs = 0; qs < 2; ++qs)
        #pragma unroll
        for (int r = 0; r < 4; ++r) { m_[qs][r] = -1e30f; L_[qs][r] = 0.0f; }

    // staging assignments
    const int sk_key = t >> 3, sk_dg = t & 7;   // K: 32 keys x 8 dim-groups
    const int sv_dim = t >> 2, sv_kg = t & 3;   // V: 64 dims x 4 key-groups
    const int k_dst = ((((sk_key >> 4) * 2 + (sk_dg >> 2)) * 64)
                       + (sk_dg & 3) * 16 + (sk_key & 15)) * 8;
    const int v_dst = (((sv_dim >> 4) * 64) + sv_kg * 16 + (sv_dim & 15)) * 8;

    const int nkt = qb / 32 + 4;
    const int wlim = qb / 32 + w;   // wave active while it <= wlim

    for (int it = 0; it < nkt; ++it) {
        const int ktb = it * 32;
        __syncthreads();
        *(uint4*)&KfL[k_dst] = *(const uint4*)
            &Kbf[(size_t)(b*SDIM + ktb + sk_key) * DDIM + hoff + sk_dg*8];
        *(uint4*)&VfL[v_dst] = *(const uint4*)
            &vT[((size_t)(b*DDIM) + hoff + sv_dim) * SDIM + ktb + sv_kg*8];
        __syncthreads();
        if (it > wlim) continue;

        short8 kf[2][2], vf[4];
        #pragma unroll
        for (int kt = 0; kt < 2; ++kt)
            #pragma unroll
            for (int kc = 0; kc < 2; ++kc)
                kf[kt][kc] = *(const short8*)&KfL[((kt*2 + kc)*64 + l) * 8];
        #pragma unroll
        for (int n = 0; n < 4; ++n)
            vf[n] = *(const short8*)&VfL[(n*64 + l) * 8];

        #pragma unroll
        for (int qs = 0; qs < 2; ++qs) {
            floatx4 s0 = {}, s1 = {};
            s0 = __builtin_amdgcn_mfma_f32_16x16x32_bf16(qf[qs][0], kf[0][0], s0, 0, 0, 0);
            s0 = __builtin_amdgcn_mfma_f32_16x16x32_bf16(qf[qs][1], kf[0][1], s0, 0, 0, 0);
            s1 = __builtin_amdgcn_mfma_f32_16x16x32_bf16(qf[qs][0], kf[1][0], s1, 0, 0, 0);
            s1 = __builtin_amdgcn_mfma_f32_16x16x32_bf16(qf[qs][1], kf[1][1], s1, 0, 0, 0);

            const int rowg0 = qwb + qs*16 + quad*4;
            float sv[2][4];
            #pragma unroll
            for (int r = 0; r < 4; ++r) {
                float x0 = s0[r] * ATT_SCALE, x1 = s1[r] * ATT_SCALE;
                if (ktb + col      > rowg0 + r) x0 = -1e30f;
                if (ktb + 16 + col > rowg0 + r) x1 = -1e30f;
                sv[0][r] = x0; sv[1][r] = x1;
            }

            float mx[4], rs[4], al[4];
            #pragma unroll
            for (int r = 0; r < 4; ++r) mx[r] = fmaxf(sv[0][r], sv[1][r]);
            #pragma unroll
            for (int msk = 1; msk <= 8; msk <<= 1)
                #pragma unroll
                for (int r = 0; r < 4; ++r) mx[r] = fmaxf(mx[r], __shfl_xor(mx[r], msk));
            #pragma unroll
            for (int r = 0; r < 4; ++r) {
                const float mn = fmaxf(m_[qs][r], mx[r]);
                al[r] = __expf(m_[qs][r] - mn);
                m_[qs][r] = mn;
                rs[r] = 0.0f;
            }
            #pragma unroll
            for (int kt = 0; kt < 2; ++kt)
                #pragma unroll
                for (int r = 0; r < 4; ++r) {
                    const float p = __expf(sv[kt][r] - m_[qs][r]);
                    sv[kt][r] = p; rs[r] += p;
                }
            #pragma unroll
            for (int msk = 1; msk <= 8; msk <<= 1)
                #pragma unroll
                for (int r = 0; r < 4; ++r) rs[r] += __shfl_xor(rs[r], msk);
            #pragma unroll
            for (int r = 0; r < 4; ++r) L_[qs][r] = L_[qs][r] * al[r] + rs[r];
            #pragma unroll
            for (int n = 0; n < 4; ++n)
                #pragma unroll
                for (int r = 0; r < 4; ++r) o_[qs][n][r] *= al[r];

            // P -> LDS (frag-linear for A-read): value (row=quad*4+r, key=kt*16+col)
            const int pbase = (w*2 + qs) * 64 * 8;
            #pragma unroll
            for (int kt = 0; kt < 2; ++kt)
                #pragma unroll
                for (int r = 0; r < 4; ++r) {
                    const int key = kt*16 + col;
                    PfL[pbase + ((key >> 3)*16 + quad*4 + r)*8 + (key & 7)]
                        = f2bf(sv[kt][r]);
                }
            const short8 pf = *(const short8*)&PfL[pbase + l*8];
            #pragma unroll
            for (int n = 0; n < 4; ++n)
                o_[qs][n] = __builtin_amdgcn_mfma_f32_16x16x32_bf16(pf, vf[n], o_[qs][n], 0, 0, 0);
        }
    }

    // epilogue: O[row][hoff + nch*16 + col] = o/l
    #pragma unroll
    for (int qs = 0; qs < 2; ++qs)
        #pragma unroll
        for (int r = 0; r < 4; ++r) {
            const float inv = 1.0f / L_[qs][r];
            const size_t row = (size_t)(b*SDIM + qwb + qs*16 + quad*4 + r);
            #pragma unroll
            for (int n = 0; n < 4; ++n)
                O[row * DDIM + hoff + n*16 + col] = o_[qs][n][r] * inv;
        }
}

extern "C" void kernel_launch(void* const* d_in, const int* in_sizes, int n_in,
                              void* d_out, int out_size, void* d_ws, size_t ws_size,
                              hipStream_t stream) {
    const float* x  = (const float*)d_in[0];
    const float* y  = (const float*)d_in[1];
    const float* Wq = (const float*)d_in[2];
    const float* bq = (const float*)d_in[3];
    const float* Wk = (const float*)d_in[4];
    const float* bk = (const float*)d_in[5];
    const float* Wv = (const float*)d_in[6];
    const float* bv = (const float*)d_in[7];
    const float* Wo = (const float*)d_in[8];
    const float* bo = (const float*)d_in[9];
    float* out = (float*)d_out;

    const size_t mat = (size_t)MDIM * DDIM;       // 4M elements
    unsigned short* wsQbf = (unsigned short*)d_ws;          // 8 MB
    unsigned short* wsKbf = wsQbf + mat;                    // 8 MB
    unsigned short* wsVT  = wsKbf + mat;                    // 8 MB
    float*          wsO   = (float*)(wsVT + mat);           // 16 MB

    dim3 gGemm(DDIM / 64, MDIM / 64);
    dim3 bGemm(256);
    hipLaunchKernelGGL(sgemm_bias_kernel<1>, gGemm, bGemm, 0, stream,
                       x, Wq, bq, (void*)wsQbf, MDIM, DDIM, DDIM);
    hipLaunchKernelGGL(sgemm_bias_kernel<1>, gGemm, bGemm, 0, stream,
                       y, Wk, bk, (void*)wsKbf, MDIM, DDIM, DDIM);
    hipLaunchKernelGGL(sgemm_bias_kernel<2>, gGemm, bGemm, 0, stream,
                       y, Wv, bv, (void*)wsVT, MDIM, DDIM, DDIM);

    dim3 gAttn(SDIM / 128, HDIM, BDIM);  // (16, 16, 2)
    hipLaunchKernelGGL(attn_mfma_kernel, gAttn, dim3(256), 0, stream,
                       wsQbf, wsKbf, wsVT, wsO);

    hipLaunchKernelGGL(sgemm_bias_kernel<0>, gGemm, bGemm, 0, stream,
                       wsO, Wo, bo, (void*)out, MDIM, DDIM, DDIM);
}

// Round 3
// 343.906 us; speedup vs baseline: 5.8145x; 2.3221x over previous
//
#include <hip/hip_runtime.h>
#include <hip/hip_bf16.h>

// CrossAttention  B=2, S=2048, D=1024, H=16, HD=64
// R3: bf16 MFMA GEMMs (m97-style: 128x128 tile, BK=32, global_load_lds w=16)
//     + MFMA flash attention (from R2, epilogue now bf16).

#define BDIM 2
#define SDIM 2048
#define DDIM 1024
#define HDIM 16
#define HD   64
#define MDIM (BDIM*SDIM)   // 4096
#define ATT_SCALE 0.125f   // 1/sqrt(64)

using short8  = __attribute__((ext_vector_type(8))) short;
using floatx4 = __attribute__((ext_vector_type(4))) float;

static __device__ __forceinline__ unsigned short f2bf(float x) {
    union { float f; unsigned int u; } c; c.f = x;
    unsigned int r = (c.u + 0x7fffu + ((c.u >> 16) & 1u)) >> 16;
    return (unsigned short)r;
}

#define GLD16(g, l) __builtin_amdgcn_global_load_lds(                        \
    (const __attribute__((address_space(1))) void*)(g),                      \
    (__attribute__((address_space(3))) void*)(l), 16, 0, 0)

// ---------------- cast fp32 -> bf16 (x and y), grid.z selects ----------------
__global__ __launch_bounds__(256) void cast_bf16_kernel(
    const float* __restrict__ X, const float* __restrict__ Y,
    unsigned short* __restrict__ Xo, unsigned short* __restrict__ Yo)
{
    const float* A          = blockIdx.z ? Y : X;
    unsigned short* O       = blockIdx.z ? Yo : Xo;
    const int idx = blockIdx.x * 256 + threadIdx.x;   // one idx = 8 elements
    const float4 a = ((const float4*)A)[idx*2];
    const float4 b = ((const float4*)A)[idx*2 + 1];
    ushort4 lo, hi;
    lo.x = f2bf(a.x); lo.y = f2bf(a.y); lo.z = f2bf(a.z); lo.w = f2bf(a.w);
    hi.x = f2bf(b.x); hi.y = f2bf(b.y); hi.z = f2bf(b.z); hi.w = f2bf(b.w);
    ((ushort4*)O)[idx*2]     = lo;
    ((ushort4*)O)[idx*2 + 1] = hi;
}

// ---------------- weight transpose-cast: Wt[n][k] = bf16(W[k][n]) ----------------
__global__ __launch_bounds__(256) void wtrans_kernel(
    const float* __restrict__ W0, const float* __restrict__ W1,
    const float* __restrict__ W2, const float* __restrict__ W3,
    unsigned short* __restrict__ T0, unsigned short* __restrict__ T1,
    unsigned short* __restrict__ T2, unsigned short* __restrict__ T3)
{
    __shared__ float tile[64][68];
    const int z = blockIdx.z;
    const float* W    = (z == 0) ? W0 : (z == 1) ? W1 : (z == 2) ? W2 : W3;
    unsigned short* T = (z == 0) ? T0 : (z == 1) ? T1 : (z == 2) ? T2 : T3;
    const int k0 = blockIdx.x * 64, n0 = blockIdx.y * 64;
    const int t = threadIdx.x;
    #pragma unroll
    for (int i = 0; i < 4; ++i) {
        const int idx = t + i*256;
        const int kr = idx >> 4, c4 = idx & 15;
        float4 v = *(const float4*)&W[(size_t)(k0 + kr) * DDIM + n0 + c4*4];
        tile[kr][c4*4+0] = v.x; tile[kr][c4*4+1] = v.y;
        tile[kr][c4*4+2] = v.z; tile[kr][c4*4+3] = v.w;
    }
    __syncthreads();
    #pragma unroll
    for (int i = 0; i < 4; ++i) {
        const int idx = t + i*256;
        const int nr = idx >> 4, kc = idx & 15;
        ushort4 o;
        o.x = f2bf(tile[kc*4+0][nr]); o.y = f2bf(tile[kc*4+1][nr]);
        o.z = f2bf(tile[kc*4+2][nr]); o.w = f2bf(tile[kc*4+3][nr]);
        *(ushort4*)&T[(size_t)(n0 + nr) * DDIM + k0 + kc*4] = o;
    }
}

// ---------------- shared 128x128 bf16 MFMA GEMM core (K=1024, BK=32) ----------------
// A row-major [M][1024] bf16, Bt row-major [N][1024] bf16 (= W^T).
// 256 thr = 4 waves; wave w -> 64x64 subtile at (w>>1, w&1); 4x4 16x16x32 MFMAs.
__device__ __forceinline__ void gemm128_core(
    const unsigned short* __restrict__ A, const unsigned short* __restrict__ Bt,
    int bm, int bn, unsigned short* As, unsigned short* Bs, floatx4 acc[4][4])
{
    const int t = threadIdx.x;
    const int w = t >> 6, l = t & 63;
    const int quad = l >> 4, col = l & 15;
    const int wr = (w >> 1) * 64, wc = (w & 1) * 64;

    const int c1 = t + 256;
    const int r0 = t >> 2,  o0 = (t & 3) * 8;
    const int r1 = c1 >> 2, o1 = (c1 & 3) * 8;

    const unsigned short* Ar0 = A  + (size_t)(bm + r0) * DDIM + o0;
    const unsigned short* Ar1 = A  + (size_t)(bm + r1) * DDIM + o1;
    const unsigned short* Br0 = Bt + (size_t)(bn + r0) * DDIM + o0;
    const unsigned short* Br1 = Bt + (size_t)(bn + r1) * DDIM + o1;

    for (int kt = 0; kt < DDIM; kt += 32) {
        __syncthreads();
        GLD16(Ar0 + kt, As + t*8);
        GLD16(Ar1 + kt, As + c1*8);
        GLD16(Br0 + kt, Bs + t*8);
        GLD16(Br1 + kt, Bs + c1*8);
        __syncthreads();
        short8 af[4], bfr[4];
        #pragma unroll
        for (int i = 0; i < 4; ++i)
            af[i] = *(const short8*)&As[(wr + i*16 + col)*32 + quad*8];
        #pragma unroll
        for (int j = 0; j < 4; ++j)
            bfr[j] = *(const short8*)&Bs[(wc + j*16 + col)*32 + quad*8];
        #pragma unroll
        for (int i = 0; i < 4; ++i)
            #pragma unroll
            for (int j = 0; j < 4; ++j)
                acc[i][j] = __builtin_amdgcn_mfma_f32_16x16x32_bf16(
                    af[i], bfr[j], acc[i][j], 0, 0, 0);
    }
}

// ---------------- fused Q/K/V projection (grid.z = 0/1/2) ----------------
__global__ __launch_bounds__(256) void qkv_gemm_kernel(
    const unsigned short* __restrict__ xbf, const unsigned short* __restrict__ ybf,
    const unsigned short* __restrict__ Wqt, const unsigned short* __restrict__ Wkt,
    const unsigned short* __restrict__ Wvt,
    const float* __restrict__ bq, const float* __restrict__ bk,
    const float* __restrict__ bv,
    unsigned short* __restrict__ Qbf, unsigned short* __restrict__ Kbf,
    unsigned short* __restrict__ vT)
{
    __shared__ __align__(16) unsigned short As[128*32];
    __shared__ __align__(16) unsigned short Bs[128*32];

    const int z = blockIdx.z;
    const unsigned short* A  = (z == 0) ? xbf : ybf;
    const unsigned short* Wt = (z == 0) ? Wqt : (z == 1) ? Wkt : Wvt;
    const float* bp          = (z == 0) ? bq  : (z == 1) ? bk  : bv;

    const int bm = blockIdx.y * 128, bn = blockIdx.x * 128;
    floatx4 acc[4][4] = {};
    gemm128_core(A, Wt, bm, bn, As, Bs, acc);

    const int t = threadIdx.x;
    const int w = t >> 6, l = t & 63;
    const int quad = l >> 4, col = l & 15;
    const int wr = (w >> 1) * 64, wc = (w & 1) * 64;

    #pragma unroll
    for (int j = 0; j < 4; ++j) {
        const int gn = bn + wc + j*16 + col;
        const float bias = bp[gn];
        #pragma unroll
        for (int i = 0; i < 4; ++i) {
            const int gm0 = bm + wr + i*16 + quad*4;
            if (z < 2) {
                unsigned short* O = (z == 0) ? Qbf : Kbf;
                #pragma unroll
                for (int r = 0; r < 4; ++r)
                    O[(size_t)(gm0 + r) * DDIM + gn] = f2bf(acc[i][j][r] + bias);
            } else {
                // vT[(b*1024 + n)][s]: 4 consecutive s per lane -> ushort4
                ushort4 o;
                o.x = f2bf(acc[i][j][0] + bias); o.y = f2bf(acc[i][j][1] + bias);
                o.z = f2bf(acc[i][j][2] + bias); o.w = f2bf(acc[i][j][3] + bias);
                *(ushort4*)&vT[((size_t)((gm0 >> 11) * DDIM + gn)) * SDIM + (gm0 & 2047)] = o;
            }
        }
    }
}

// ---------------- output projection: fp32 out = Obf @ Wo + bo ----------------
__global__ __launch_bounds__(256) void out_gemm_kernel(
    const unsigned short* __restrict__ Obf, const unsigned short* __restrict__ Wot,
    const float* __restrict__ bo, float* __restrict__ out)
{
    __shared__ __align__(16) unsigned short As[128*32];
    __shared__ __align__(16) unsigned short Bs[128*32];

    const int bm = blockIdx.y * 128, bn = blockIdx.x * 128;
    floatx4 acc[4][4] = {};
    gemm128_core(Obf, Wot, bm, bn, As, Bs, acc);

    const int t = threadIdx.x;
    const int w = t >> 6, l = t & 63;
    const int quad = l >> 4, col = l & 15;
    const int wr = (w >> 1) * 64, wc = (w & 1) * 64;

    #pragma unroll
    for (int j = 0; j < 4; ++j) {
        const int gn = bn + wc + j*16 + col;
        const float bias = bo[gn];
        #pragma unroll
        for (int i = 0; i < 4; ++i) {
            const int gm0 = bm + wr + i*16 + quad*4;
            #pragma unroll
            for (int r = 0; r < 4; ++r)
                out[(size_t)(gm0 + r) * DDIM + gn] = acc[i][j][r] + bias;
        }
    }
}

// ---------------- MFMA flash attention (R2, bf16 epilogue) ----------------
__global__ __launch_bounds__(256) void attn_mfma_kernel(
    const unsigned short* __restrict__ Qbf, const unsigned short* __restrict__ Kbf,
    const unsigned short* __restrict__ vT, unsigned short* __restrict__ Obf)
{
    __shared__ __align__(16) unsigned short KfL[4*64*8];
    __shared__ __align__(16) unsigned short VfL[4*64*8];
    __shared__ __align__(16) unsigned short PfL[8*64*8];

    const int t    = threadIdx.x;
    const int w    = t >> 6;
    const int l    = t & 63;
    const int quad = l >> 4, col = l & 15;
    const int qb   = blockIdx.x * 128;
    const int h    = blockIdx.y, b = blockIdx.z;
    const int qwb  = qb + w * 32;
    const size_t hoff = (size_t)h * HD;

    short8 qf[2][2];
    #pragma unroll
    for (int qs = 0; qs < 2; ++qs)
        #pragma unroll
        for (int kc = 0; kc < 2; ++kc)
            qf[qs][kc] = *(const short8*)
                &Qbf[(size_t)(b*SDIM + qwb + qs*16 + col) * DDIM + hoff + kc*32 + quad*8];

    floatx4 o_[2][4] = {};
    float m_[2][4], L_[2][4];
    #pragma unroll
    for (int qs = 0; qs < 2; ++qs)
        #pragma unroll
        for (int r = 0; r < 4; ++r) { m_[qs][r] = -1e30f; L_[qs][r] = 0.0f; }

    const int sk_key = t >> 3, sk_dg = t & 7;
    const int sv_dim = t >> 2, sv_kg = t & 3;
    const int k_dst = ((((sk_key >> 4) * 2 + (sk_dg >> 2)) * 64)
                       + (sk_dg & 3) * 16 + (sk_key & 15)) * 8;
    const int v_dst = (((sv_dim >> 4) * 64) + sv_kg * 16 + (sv_dim & 15)) * 8;

    const int nkt = qb / 32 + 4;
    const int wlim = qb / 32 + w;

    for (int it = 0; it < nkt; ++it) {
        const int ktb = it * 32;
        __syncthreads();
        *(uint4*)&KfL[k_dst] = *(const uint4*)
            &Kbf[(size_t)(b*SDIM + ktb + sk_key) * DDIM + hoff + sk_dg*8];
        *(uint4*)&VfL[v_dst] = *(const uint4*)
            &vT[((size_t)(b*DDIM) + hoff + sv_dim) * SDIM + ktb + sv_kg*8];
        __syncthreads();
        if (it > wlim) continue;

        short8 kf[2][2], vf[4];
        #pragma unroll
        for (int kt = 0; kt < 2; ++kt)
            #pragma unroll
            for (int kc = 0; kc < 2; ++kc)
                kf[kt][kc] = *(const short8*)&KfL[((kt*2 + kc)*64 + l) * 8];
        #pragma unroll
        for (int n = 0; n < 4; ++n)
            vf[n] = *(const short8*)&VfL[(n*64 + l) * 8];

        #pragma unroll
        for (int qs = 0; qs < 2; ++qs) {
            floatx4 s0 = {}, s1 = {};
            s0 = __builtin_amdgcn_mfma_f32_16x16x32_bf16(qf[qs][0], kf[0][0], s0, 0, 0, 0);
            s0 = __builtin_amdgcn_mfma_f32_16x16x32_bf16(qf[qs][1], kf[0][1], s0, 0, 0, 0);
            s1 = __builtin_amdgcn_mfma_f32_16x16x32_bf16(qf[qs][0], kf[1][0], s1, 0, 0, 0);
            s1 = __builtin_amdgcn_mfma_f32_16x16x32_bf16(qf[qs][1], kf[1][1], s1, 0, 0, 0);

            const int rowg0 = qwb + qs*16 + quad*4;
            float sv[2][4];
            #pragma unroll
            for (int r = 0; r < 4; ++r) {
                float x0 = s0[r] * ATT_SCALE, x1 = s1[r] * ATT_SCALE;
                if (ktb + col      > rowg0 + r) x0 = -1e30f;
                if (ktb + 16 + col > rowg0 + r) x1 = -1e30f;
                sv[0][r] = x0; sv[1][r] = x1;
            }

            float mx[4], rs[4], al[4];
            #pragma unroll
            for (int r = 0; r < 4; ++r) mx[r] = fmaxf(sv[0][r], sv[1][r]);
            #pragma unroll
            for (int msk = 1; msk <= 8; msk <<= 1)
                #pragma unroll
                for (int r = 0; r < 4; ++r) mx[r] = fmaxf(mx[r], __shfl_xor(mx[r], msk));
            #pragma unroll
            for (int r = 0; r < 4; ++r) {
                const float mn = fmaxf(m_[qs][r], mx[r]);
                al[r] = __expf(m_[qs][r] - mn);
                m_[qs][r] = mn;
                rs[r] = 0.0f;
            }
            #pragma unroll
            for (int kt = 0; kt < 2; ++kt)
                #pragma unroll
                for (int r = 0; r < 4; ++r) {
                    const float p = __expf(sv[kt][r] - m_[qs][r]);
                    sv[kt][r] = p; rs[r] += p;
                }
            #pragma unroll
            for (int msk = 1; msk <= 8; msk <<= 1)
                #pragma unroll
                for (int r = 0; r < 4; ++r) rs[r] += __shfl_xor(rs[r], msk);
            #pragma unroll
            for (int r = 0; r < 4; ++r) L_[qs][r] = L_[qs][r] * al[r] + rs[r];
            #pragma unroll
            for (int n = 0; n < 4; ++n)
                #pragma unroll
                for (int r = 0; r < 4; ++r) o_[qs][n][r] *= al[r];

            const int pbase = (w*2 + qs) * 64 * 8;
            #pragma unroll
            for (int kt = 0; kt < 2; ++kt)
                #pragma unroll
                for (int r = 0; r < 4; ++r) {
                    const int key = kt*16 + col;
                    PfL[pbase + ((key >> 3)*16 + quad*4 + r)*8 + (key & 7)]
                        = f2bf(sv[kt][r]);
                }
            const short8 pf = *(const short8*)&PfL[pbase + l*8];
            #pragma unroll
            for (int n = 0; n < 4; ++n)
                o_[qs][n] = __builtin_amdgcn_mfma_f32_16x16x32_bf16(pf, vf[n], o_[qs][n], 0, 0, 0);
        }
    }

    #pragma unroll
    for (int qs = 0; qs < 2; ++qs)
        #pragma unroll
        for (int r = 0; r < 4; ++r) {
            const float inv = 1.0f / L_[qs][r];
            const size_t row = (size_t)(b*SDIM + qwb + qs*16 + quad*4 + r);
            #pragma unroll
            for (int n = 0; n < 4; ++n)
                Obf[row * DDIM + hoff + n*16 + col] = f2bf(o_[qs][n][r] * inv);
        }
}

extern "C" void kernel_launch(void* const* d_in, const int* in_sizes, int n_in,
                              void* d_out, int out_size, void* d_ws, size_t ws_size,
                              hipStream_t stream) {
    const float* x  = (const float*)d_in[0];
    const float* y  = (const float*)d_in[1];
    const float* Wq = (const float*)d_in[2];
    const float* bq = (const float*)d_in[3];
    const float* Wk = (const float*)d_in[4];
    const float* bk = (const float*)d_in[5];
    const float* Wv = (const float*)d_in[6];
    const float* bv = (const float*)d_in[7];
    const float* Wo = (const float*)d_in[8];
    const float* bo = (const float*)d_in[9];
    float* out = (float*)d_out;

    const size_t mat  = (size_t)MDIM * DDIM;   // 4M elements
    const size_t wmat = (size_t)DDIM * DDIM;   // 1M elements
    unsigned short* p = (unsigned short*)d_ws;
    unsigned short* xbf = p;            p += mat;
    unsigned short* ybf = p;            p += mat;
    unsigned short* Wqt = p;            p += wmat;
    unsigned short* Wkt = p;            p += wmat;
    unsigned short* Wvt = p;            p += wmat;
    unsigned short* Wot = p;            p += wmat;
    unsigned short* Qbf = p;            p += mat;
    unsigned short* Kbf = p;            p += mat;
    unsigned short* vT  = p;            p += mat;
    unsigned short* Obf = p;            p += mat;   // total 56 MB

    hipLaunchKernelGGL(cast_bf16_kernel, dim3(MDIM*DDIM/8/256, 1, 2), dim3(256),
                       0, stream, x, y, xbf, ybf);
    hipLaunchKernelGGL(wtrans_kernel, dim3(16, 16, 4), dim3(256), 0, stream,
                       Wq, Wk, Wv, Wo, Wqt, Wkt, Wvt, Wot);

    hipLaunchKernelGGL(qkv_gemm_kernel, dim3(DDIM/128, MDIM/128, 3), dim3(256),
                       0, stream, xbf, ybf, Wqt, Wkt, Wvt, bq, bk, bv,
                       Qbf, Kbf, vT);

    hipLaunchKernelGGL(attn_mfma_kernel, dim3(SDIM/128, HDIM, BDIM), dim3(256),
                       0, stream, Qbf, Kbf, vT, Obf);

    hipLaunchKernelGGL(out_gemm_kernel, dim3(DDIM/128, MDIM/128), dim3(256),
                       0, stream, Obf, Wot, bo, out);
}

// Round 4
// 250.540 us; speedup vs baseline: 7.9813x; 1.3727x over previous
//
#include <hip/hip_runtime.h>
#include <hip/hip_bf16.h>

// CrossAttention  B=2, S=2048, D=1024, H=16, HD=64
// R4: attention rewritten — work-balanced paired q-tiles, transposed S^T=K*Q^T
// softmax (in-register key reduction, 2 shuffle stages), 64-key iterations.
// GEMM pipeline (bf16 MFMA 128x128, global_load_lds) unchanged from R3.

#define BDIM 2
#define SDIM 2048
#define DDIM 1024
#define HDIM 16
#define HD   64
#define MDIM (BDIM*SDIM)   // 4096
// softmax in exp2 domain: score * (1/8) * log2(e)
#define C2 0.18033688011112042f

using short8  = __attribute__((ext_vector_type(8))) short;
using floatx4 = __attribute__((ext_vector_type(4))) float;

static __device__ __forceinline__ unsigned short f2bf(float x) {
    union { float f; unsigned int u; } c; c.f = x;
    unsigned int r = (c.u + 0x7fffu + ((c.u >> 16) & 1u)) >> 16;
    return (unsigned short)r;
}

#define GLD16(g, l) __builtin_amdgcn_global_load_lds(                        \
    (const __attribute__((address_space(1))) void*)(g),                      \
    (__attribute__((address_space(3))) void*)(l), 16, 0, 0)

// ---------------- cast fp32 -> bf16 (x and y) ----------------
__global__ __launch_bounds__(256) void cast_bf16_kernel(
    const float* __restrict__ X, const float* __restrict__ Y,
    unsigned short* __restrict__ Xo, unsigned short* __restrict__ Yo)
{
    const float* A    = blockIdx.z ? Y : X;
    unsigned short* O = blockIdx.z ? Yo : Xo;
    const int idx = blockIdx.x * 256 + threadIdx.x;
    const float4 a = ((const float4*)A)[idx*2];
    const float4 b = ((const float4*)A)[idx*2 + 1];
    ushort4 lo, hi;
    lo.x = f2bf(a.x); lo.y = f2bf(a.y); lo.z = f2bf(a.z); lo.w = f2bf(a.w);
    hi.x = f2bf(b.x); hi.y = f2bf(b.y); hi.z = f2bf(b.z); hi.w = f2bf(b.w);
    ((ushort4*)O)[idx*2]     = lo;
    ((ushort4*)O)[idx*2 + 1] = hi;
}

// ---------------- weight transpose-cast: Wt[n][k] = bf16(W[k][n]) ----------------
__global__ __launch_bounds__(256) void wtrans_kernel(
    const float* __restrict__ W0, const float* __restrict__ W1,
    const float* __restrict__ W2, const float* __restrict__ W3,
    unsigned short* __restrict__ T0, unsigned short* __restrict__ T1,
    unsigned short* __restrict__ T2, unsigned short* __restrict__ T3)
{
    __shared__ float tile[64][68];
    const int z = blockIdx.z;
    const float* W    = (z == 0) ? W0 : (z == 1) ? W1 : (z == 2) ? W2 : W3;
    unsigned short* T = (z == 0) ? T0 : (z == 1) ? T1 : (z == 2) ? T2 : T3;
    const int k0 = blockIdx.x * 64, n0 = blockIdx.y * 64;
    const int t = threadIdx.x;
    #pragma unroll
    for (int i = 0; i < 4; ++i) {
        const int idx = t + i*256;
        const int kr = idx >> 4, c4 = idx & 15;
        float4 v = *(const float4*)&W[(size_t)(k0 + kr) * DDIM + n0 + c4*4];
        tile[kr][c4*4+0] = v.x; tile[kr][c4*4+1] = v.y;
        tile[kr][c4*4+2] = v.z; tile[kr][c4*4+3] = v.w;
    }
    __syncthreads();
    #pragma unroll
    for (int i = 0; i < 4; ++i) {
        const int idx = t + i*256;
        const int nr = idx >> 4, kc = idx & 15;
        ushort4 o;
        o.x = f2bf(tile[kc*4+0][nr]); o.y = f2bf(tile[kc*4+1][nr]);
        o.z = f2bf(tile[kc*4+2][nr]); o.w = f2bf(tile[kc*4+3][nr]);
        *(ushort4*)&T[(size_t)(n0 + nr) * DDIM + k0 + kc*4] = o;
    }
}

// ---------------- shared 128x128 bf16 MFMA GEMM core (K=1024, BK=32) ----------------
__device__ __forceinline__ void gemm128_core(
    const unsigned short* __restrict__ A, const unsigned short* __restrict__ Bt,
    int bm, int bn, unsigned short* As, unsigned short* Bs, floatx4 acc[4][4])
{
    const int t = threadIdx.x;
    const int w = t >> 6, l = t & 63;
    const int quad = l >> 4, col = l & 15;
    const int wr = (w >> 1) * 64, wc = (w & 1) * 64;

    const int c1 = t + 256;
    const int r0 = t >> 2,  o0 = (t & 3) * 8;
    const int r1 = c1 >> 2, o1 = (c1 & 3) * 8;

    const unsigned short* Ar0 = A  + (size_t)(bm + r0) * DDIM + o0;
    const unsigned short* Ar1 = A  + (size_t)(bm + r1) * DDIM + o1;
    const unsigned short* Br0 = Bt + (size_t)(bn + r0) * DDIM + o0;
    const unsigned short* Br1 = Bt + (size_t)(bn + r1) * DDIM + o1;

    for (int kt = 0; kt < DDIM; kt += 32) {
        __syncthreads();
        GLD16(Ar0 + kt, As + t*8);
        GLD16(Ar1 + kt, As + c1*8);
        GLD16(Br0 + kt, Bs + t*8);
        GLD16(Br1 + kt, Bs + c1*8);
        __syncthreads();
        short8 af[4], bfr[4];
        #pragma unroll
        for (int i = 0; i < 4; ++i)
            af[i] = *(const short8*)&As[(wr + i*16 + col)*32 + quad*8];
        #pragma unroll
        for (int j = 0; j < 4; ++j)
            bfr[j] = *(const short8*)&Bs[(wc + j*16 + col)*32 + quad*8];
        #pragma unroll
        for (int i = 0; i < 4; ++i)
            #pragma unroll
            for (int j = 0; j < 4; ++j)
                acc[i][j] = __builtin_amdgcn_mfma_f32_16x16x32_bf16(
                    af[i], bfr[j], acc[i][j], 0, 0, 0);
    }
}

// ---------------- fused Q/K/V projection (grid.z = 0/1/2) ----------------
__global__ __launch_bounds__(256) void qkv_gemm_kernel(
    const unsigned short* __restrict__ xbf, const unsigned short* __restrict__ ybf,
    const unsigned short* __restrict__ Wqt, const unsigned short* __restrict__ Wkt,
    const unsigned short* __restrict__ Wvt,
    const float* __restrict__ bq, const float* __restrict__ bk,
    const float* __restrict__ bv,
    unsigned short* __restrict__ Qbf, unsigned short* __restrict__ Kbf,
    unsigned short* __restrict__ vT)
{
    __shared__ __align__(16) unsigned short As[128*32];
    __shared__ __align__(16) unsigned short Bs[128*32];

    const int z = blockIdx.z;
    const unsigned short* A  = (z == 0) ? xbf : ybf;
    const unsigned short* Wt = (z == 0) ? Wqt : (z == 1) ? Wkt : Wvt;
    const float* bp          = (z == 0) ? bq  : (z == 1) ? bk  : bv;

    const int bm = blockIdx.y * 128, bn = blockIdx.x * 128;
    floatx4 acc[4][4] = {};
    gemm128_core(A, Wt, bm, bn, As, Bs, acc);

    const int t = threadIdx.x;
    const int w = t >> 6, l = t & 63;
    const int quad = l >> 4, col = l & 15;
    const int wr = (w >> 1) * 64, wc = (w & 1) * 64;

    #pragma unroll
    for (int j = 0; j < 4; ++j) {
        const int gn = bn + wc + j*16 + col;
        const float bias = bp[gn];
        #pragma unroll
        for (int i = 0; i < 4; ++i) {
            const int gm0 = bm + wr + i*16 + quad*4;
            if (z < 2) {
                unsigned short* O = (z == 0) ? Qbf : Kbf;
                #pragma unroll
                for (int r = 0; r < 4; ++r)
                    O[(size_t)(gm0 + r) * DDIM + gn] = f2bf(acc[i][j][r] + bias);
            } else {
                ushort4 o;
                o.x = f2bf(acc[i][j][0] + bias); o.y = f2bf(acc[i][j][1] + bias);
                o.z = f2bf(acc[i][j][2] + bias); o.w = f2bf(acc[i][j][3] + bias);
                *(ushort4*)&vT[((size_t)((gm0 >> 11) * DDIM + gn)) * SDIM + (gm0 & 2047)] = o;
            }
        }
    }
}

// ---------------- output projection: fp32 out = Obf @ Wo + bo ----------------
__global__ __launch_bounds__(256) void out_gemm_kernel(
    const unsigned short* __restrict__ Obf, const unsigned short* __restrict__ Wot,
    const float* __restrict__ bo, float* __restrict__ out)
{
    __shared__ __align__(16) unsigned short As[128*32];
    __shared__ __align__(16) unsigned short Bs[128*32];

    const int bm = blockIdx.y * 128, bn = blockIdx.x * 128;
    floatx4 acc[4][4] = {};
    gemm128_core(Obf, Wot, bm, bn, As, Bs, acc);

    const int t = threadIdx.x;
    const int w = t >> 6, l = t & 63;
    const int quad = l >> 4, col = l & 15;
    const int wr = (w >> 1) * 64, wc = (w & 1) * 64;

    #pragma unroll
    for (int j = 0; j < 4; ++j) {
        const int gn = bn + wc + j*16 + col;
        const float bias = bo[gn];
        #pragma unroll
        for (int i = 0; i < 4; ++i) {
            const int gm0 = bm + wr + i*16 + quad*4;
            #pragma unroll
            for (int r = 0; r < 4; ++r)
                out[(size_t)(gm0 + r) * DDIM + gn] = acc[i][j][r] + bias;
        }
    }
}

// ---------------- MFMA flash attention, transposed-softmax, balanced ----------------
// Block j handles q-tiles j and 31-j (64 rows each): exactly 33 x 64-key iters.
// 4 waves x 16 q rows. S^T = K*Q^T so each lane owns one q (col) and 16 keys
// in-register; softmax reduce = in-reg tree + 2 shuffles. O^T = V^T * P^T.
__global__ __launch_bounds__(256) void attn_mfma_kernel(
    const unsigned short* __restrict__ Qbf, const unsigned short* __restrict__ Kbf,
    const unsigned short* __restrict__ vT, unsigned short* __restrict__ Obf)
{
    __shared__ __align__(16) unsigned short KfL[8*64*8];   // 8 KB
    __shared__ __align__(16) unsigned short VfL[8*64*8];   // 8 KB
    __shared__ __align__(16) unsigned short PfL[4*1024];   // 8 KB (per-wave 1024)

    const int t = threadIdx.x;
    const int w = t >> 6, l = t & 63;
    const int quad = l >> 4, col = l & 15;
    const int jt = blockIdx.x;          // 0..15
    const int h  = blockIdx.y, b = blockIdx.z;
    const size_t hoff = (size_t)h * HD;
    const size_t bS = (size_t)b * SDIM;
    const size_t bD = (size_t)b * DDIM;
    const int skey = t >> 3, sdp = t & 7;   // staging: 8 threads per 128B row
    const int pb = w * 1024;

    #pragma unroll 1
    for (int ph = 0; ph < 2; ++ph) {
        const int qt  = ph ? (31 - jt) : jt;
        const int qb  = qt * 64;
        const int qwb = qb + w * 16;
        const int nk  = qt + 1;

        // Q fragment (B-operand: n=col=q, k=quad*8+j over dims)
        short8 qf[2];
        #pragma unroll
        for (int kc = 0; kc < 2; ++kc)
            qf[kc] = *(const short8*)
                &Qbf[(bS + qwb + col) * DDIM + hoff + kc*32 + quad*8];

        float mrun = -1e30f, lrun = 0.0f;
        floatx4 o[4] = {};

        for (int it = 0; it < nk; ++it) {
            const int ktb = it * 64;
            __syncthreads();
            #pragma unroll
            for (int rr = 0; rr < 2; ++rr) {
                const int key = rr*32 + skey;
                const int dst = (((key>>4)*2 + (sdp>>2))*64 + (sdp&3)*16 + (key&15))*8;
                *(uint4*)&KfL[dst] = *(const uint4*)
                    &Kbf[(bS + ktb + key) * DDIM + hoff + sdp*8];
                const int d = rr*32 + skey;
                const int vdst = (((d>>4)*2 + (sdp>>2))*64 + (sdp&3)*16 + (d&15))*8;
                *(uint4*)&VfL[vdst] = *(const uint4*)
                    &vT[(bD + hoff + d) * SDIM + ktb + sdp*8];
            }
            __syncthreads();

            short8 kf[4][2], vf[4][2];
            #pragma unroll
            for (int kt = 0; kt < 4; ++kt)
                #pragma unroll
                for (int kc = 0; kc < 2; ++kc)
                    kf[kt][kc] = *(const short8*)&KfL[((kt*2 + kc)*64 + l)*8];
            #pragma unroll
            for (int n = 0; n < 4; ++n)
                #pragma unroll
                for (int kk = 0; kk < 2; ++kk)
                    vf[n][kk] = *(const short8*)&VfL[((n*2 + kk)*64 + l)*8];

            // S^T = K * Q^T : lane holds keys {kt*16+quad*4+r}, q = col
            floatx4 sT[4];
            #pragma unroll
            for (int kt = 0; kt < 4; ++kt) {
                floatx4 z = {};
                z = __builtin_amdgcn_mfma_f32_16x16x32_bf16(kf[kt][0], qf[0], z, 0, 0, 0);
                z = __builtin_amdgcn_mfma_f32_16x16x32_bf16(kf[kt][1], qf[1], z, 0, 0, 0);
                sT[kt] = z;
            }

            float p[4][4];
            const bool masked = (ktb + 63 > qwb);
            #pragma unroll
            for (int kt = 0; kt < 4; ++kt)
                #pragma unroll
                for (int r = 0; r < 4; ++r) {
                    float xv = sT[kt][r] * C2;
                    if (masked && (ktb + kt*16 + quad*4 + r > qwb + col))
                        xv = -3.0e38f;
                    p[kt][r] = xv;
                }

            // max tree (in-lane 16) + 2 shuffle stages over quads
            float mt[4];
            #pragma unroll
            for (int kt = 0; kt < 4; ++kt)
                mt[kt] = fmaxf(fmaxf(p[kt][0], p[kt][1]), fmaxf(p[kt][2], p[kt][3]));
            float mx = fmaxf(fmaxf(mt[0], mt[1]), fmaxf(mt[2], mt[3]));
            mx = fmaxf(mx, __shfl_xor(mx, 16));
            mx = fmaxf(mx, __shfl_xor(mx, 32));
            const float mnew  = fmaxf(mrun, mx);
            const float alpha = exp2f(mrun - mnew);
            mrun = mnew;

            #pragma unroll
            for (int kt = 0; kt < 4; ++kt)
                #pragma unroll
                for (int r = 0; r < 4; ++r)
                    p[kt][r] = exp2f(p[kt][r] - mnew);

            float st[4];
            #pragma unroll
            for (int kt = 0; kt < 4; ++kt)
                st[kt] = (p[kt][0] + p[kt][1]) + (p[kt][2] + p[kt][3]);
            const float rs = (st[0] + st[1]) + (st[2] + st[3]);
            lrun = lrun * alpha + rs;   // per-lane partial (keys of this quad)

            #pragma unroll
            for (int n = 0; n < 4; ++n)
                #pragma unroll
                for (int r = 0; r < 4; ++r)
                    o[n][r] *= alpha;

            // P^T -> LDS in B-frag layout: slot((key,q)) = ((key>>3)*16+q)*8 + (key&7)
            #pragma unroll
            for (int kt = 0; kt < 4; ++kt) {
                ushort4 pk;
                pk.x = f2bf(p[kt][0]); pk.y = f2bf(p[kt][1]);
                pk.z = f2bf(p[kt][2]); pk.w = f2bf(p[kt][3]);
                *(ushort4*)&PfL[pb + ((kt*2 + (quad>>1))*16 + col)*8 + (quad&1)*4] = pk;
            }
            short8 pf0 = *(const short8*)&PfL[pb + ((0*4 + quad)*16 + col)*8];
            short8 pf1 = *(const short8*)&PfL[pb + ((1*4 + quad)*16 + col)*8];
            #pragma unroll
            for (int n = 0; n < 4; ++n) {
                o[n] = __builtin_amdgcn_mfma_f32_16x16x32_bf16(vf[n][0], pf0, o[n], 0, 0, 0);
                o[n] = __builtin_amdgcn_mfma_f32_16x16x32_bf16(vf[n][1], pf1, o[n], 0, 0, 0);
            }
        }

        // epilogue: reduce l over quads, write O row q=col
        float lt = lrun;
        lt += __shfl_xor(lt, 16);
        lt += __shfl_xor(lt, 32);
        const float inv = 1.0f / lt;
        #pragma unroll
        for (int n = 0; n < 4; ++n) {
            ushort4 pk;
            pk.x = f2bf(o[n][0] * inv); pk.y = f2bf(o[n][1] * inv);
            pk.z = f2bf(o[n][2] * inv); pk.w = f2bf(o[n][3] * inv);
            *(ushort4*)&Obf[(bS + qwb + col) * DDIM + hoff + n*16 + quad*4] = pk;
        }
    }
}

extern "C" void kernel_launch(void* const* d_in, const int* in_sizes, int n_in,
                              void* d_out, int out_size, void* d_ws, size_t ws_size,
                              hipStream_t stream) {
    const float* x  = (const float*)d_in[0];
    const float* y  = (const float*)d_in[1];
    const float* Wq = (const float*)d_in[2];
    const float* bq = (const float*)d_in[3];
    const float* Wk = (const float*)d_in[4];
    const float* bk = (const float*)d_in[5];
    const float* Wv = (const float*)d_in[6];
    const float* bv = (const float*)d_in[7];
    const float* Wo = (const float*)d_in[8];
    const float* bo = (const float*)d_in[9];
    float* out = (float*)d_out;

    const size_t mat  = (size_t)MDIM * DDIM;
    const size_t wmat = (size_t)DDIM * DDIM;
    unsigned short* p = (unsigned short*)d_ws;
    unsigned short* xbf = p;            p += mat;
    unsigned short* ybf = p;            p += mat;
    unsigned short* Wqt = p;            p += wmat;
    unsigned short* Wkt = p;            p += wmat;
    unsigned short* Wvt = p;            p += wmat;
    unsigned short* Wot = p;            p += wmat;
    unsigned short* Qbf = p;            p += mat;
    unsigned short* Kbf = p;            p += mat;
    unsigned short* vT  = p;            p += mat;
    unsigned short* Obf = p;            p += mat;

    hipLaunchKernelGGL(cast_bf16_kernel, dim3(MDIM*DDIM/8/256, 1, 2), dim3(256),
                       0, stream, x, y, xbf, ybf);
    hipLaunchKernelGGL(wtrans_kernel, dim3(16, 16, 4), dim3(256), 0, stream,
                       Wq, Wk, Wv, Wo, Wqt, Wkt, Wvt, Wot);

    hipLaunchKernelGGL(qkv_gemm_kernel, dim3(DDIM/128, MDIM/128, 3), dim3(256),
                       0, stream, xbf, ybf, Wqt, Wkt, Wvt, bq, bk, bv,
                       Qbf, Kbf, vT);

    hipLaunchKernelGGL(attn_mfma_kernel, dim3(16, HDIM, BDIM), dim3(256),
                       0, stream, Qbf, Kbf, vT, Obf);

    hipLaunchKernelGGL(out_gemm_kernel, dim3(DDIM/128, MDIM/128), dim3(256),
                       0, stream, Obf, Wot, bo, out);
}